// Round 2
// baseline (14751.949 us; speedup 1.0000x reference)
//
#include <hip/hip_runtime.h>
#include <cstdint>
#include <cstddef>

// LSTM decoder B=256,H=1024,T=128. Persistent cooperative-style kernel:
// 256 blocks x 512 thr (1 block/CU, 2 waves/SIMD). Each block owns 8 cols
// x 4 gates (packed N=32), weights hi/lo bf16 in 128KB LDS (XOR-swizzled),
// 3-pass bf16 MFMA (h1@W1 + h2@W1 + h1@W2 ~ fp32). c/xpre in registers.
// Grid barrier (device-scope atomic + fences) between steps.

#define DI __device__ __forceinline__

typedef __attribute__((ext_vector_type(8))) short short8;
typedef __attribute__((ext_vector_type(4))) float f32x4;
typedef unsigned short u16;
typedef unsigned int   u32;

static constexpr int H = 1024;
static constexpr int B = 256;
static constexpr int T = 128;

DI u16 f2bf(float f){
  union { float f; u32 u; } v; v.f = f;
  u32 r = v.u + 0x7fffu + ((v.u >> 16) & 1u);
  return (u16)(r >> 16);
}
DI float bf2f(u16 h){
  union { u32 u; float f; } v; v.u = ((u32)h) << 16; return v.f;
}
DI float sigf(float z){ return 1.0f / (1.0f + __expf(-z)); }
DI float tanh_(float z){
  float e = __expf(-2.0f * fabsf(z));
  float t = (1.0f - e) / (1.0f + e);
  return z < 0.0f ? -t : t;
}

struct P {
  const float *x;
  const float *Wxi,*Wxf,*Wxo,*Wxc;
  const float *Whi,*Whf,*Who,*Whc;
  const float *bxi,*bxf,*bxo,*bxc;
  const float *bhi,*bhf,*bho,*bhc;
  float* out;
  char*  hb;    // 2 x 1MB parity buffers: [row][kb][plane][8] bf16
  u32*   bar;   // grid barrier counter (memset 0 before launch)
};

// Pack the block's 32 packed-N weight rows x K=1024 into LDS (hi plane at 0,
// lo plane at 64KB), XOR-swizzled. Packed row q: tile t=q>>4, qq=q&15,
// gate = t*2 + (qq&1) [t0:(i,f) t1:(o,c)], col = bn*8 + (qq>>1).
DI void pack_w(char* lds, int bn, int tid,
               const float* Wi, const float* Wf, const float* Wo, const float* Wc){
  #pragma unroll
  for (int i = 0; i < 8; ++i){
    int j0 = tid + i * 512;            // 4096 jobs: (q, 16B k-chunk)
    int q  = j0 >> 7;
    int kc = j0 & 127;
    int qq = q & 15;
    const float* Wg = (q & 16) ? ((qq & 1) ? Wc : Wo) : ((qq & 1) ? Wf : Wi);
    const float* src = Wg + (size_t)(bn * 8 + (qq >> 1)) * 1024 + kc * 8;
    f32x4 v0 = *(const f32x4*)(src);
    f32x4 v1 = *(const f32x4*)(src + 4);
    short8 hi, lo;
    #pragma unroll
    for (int e = 0; e < 4; ++e){
      u16 h0 = f2bf(v0[e]); hi[e]     = (short)h0; lo[e]     = (short)f2bf(v0[e] - bf2f(h0));
      u16 h1 = f2bf(v1[e]); hi[4 + e] = (short)h1; lo[4 + e] = (short)f2bf(v1[e] - bf2f(h1));
    }
    int addr = (q * 2048 + kc * 16) ^ ((q & 7) << 4);
    *(short8*)(lds + addr)         = hi;
    *(short8*)(lds + 65536 + addr) = lo;
  }
}

__global__ __launch_bounds__(512, 2) void lstm_kernel(P p){
  __shared__ char lds[131072];
  const int tid  = threadIdx.x;
  const int lane = tid & 63;
  const int w    = tid >> 6;              // wave 0..7 -> M-tile
  const int l15  = lane & 15;
  const int lhi  = lane >> 4;
  const int l7   = lane & 7;
  const int blk  = blockIdx.x;
  const int bn   = blk >> 1;              // col-group 0..127
  const int rg   = blk & 1;               // row-group
  const int rowbase = rg * 128 + w * 16;
  const int col  = bn * 8 + (l15 >> 1);
  const bool odd = (l15 & 1);

  // swizzled-LDS lane constants (B-fragment addressing)
  const int lin0 = l15 * 2048 + lhi * 16;
  const int lin1 = (16 + l15) * 2048 + lhi * 16;
  const int m    = l7 << 4;

  // ---- phase 1: pack Wx -> LDS, compute xpre (this block's 128 rows) in regs
  pack_w(lds, bn, tid, p.Wxi, p.Wxf, p.Wxo, p.Wxc);
  __syncthreads();

  f32x4 xp0 = {0.f,0.f,0.f,0.f}, xp1 = {0.f,0.f,0.f,0.f};
  {
    const float* xr = p.x + (size_t)(rowbase + l15) * 1024 + lhi * 8;
    for (int k0 = 0; k0 < 1024; k0 += 32){
      f32x4 v0 = *(const f32x4*)(xr + k0);
      f32x4 v1 = *(const f32x4*)(xr + k0 + 4);
      short8 a1, a2;
      #pragma unroll
      for (int e = 0; e < 4; ++e){
        u16 h0 = f2bf(v0[e]); a1[e]     = (short)h0; a2[e]     = (short)f2bf(v0[e] - bf2f(h0));
        u16 h1 = f2bf(v1[e]); a1[4 + e] = (short)h1; a2[4 + e] = (short)f2bf(v1[e] - bf2f(h1));
      }
      int s0 = (lin0 + k0 * 2) ^ m;
      int s1 = (lin1 + k0 * 2) ^ m;
      short8 b10 = *(const short8*)(lds + s0);
      short8 b20 = *(const short8*)(lds + 65536 + s0);
      short8 b11 = *(const short8*)(lds + s1);
      short8 b21 = *(const short8*)(lds + 65536 + s1);
      xp0 = __builtin_amdgcn_mfma_f32_16x16x32_bf16(a1, b10, xp0, 0,0,0);
      xp0 = __builtin_amdgcn_mfma_f32_16x16x32_bf16(a2, b10, xp0, 0,0,0);
      xp0 = __builtin_amdgcn_mfma_f32_16x16x32_bf16(a1, b20, xp0, 0,0,0);
      xp1 = __builtin_amdgcn_mfma_f32_16x16x32_bf16(a1, b11, xp1, 0,0,0);
      xp1 = __builtin_amdgcn_mfma_f32_16x16x32_bf16(a2, b11, xp1, 0,0,0);
      xp1 = __builtin_amdgcn_mfma_f32_16x16x32_bf16(a1, b21, xp1, 0,0,0);
    }
    float bx0 = odd ? p.bxf[col] : p.bxi[col];
    float bh0 = odd ? p.bhf[col] : p.bhi[col];
    float bx1 = odd ? p.bxc[col] : p.bxo[col];
    float bh1 = odd ? p.bhc[col] : p.bho[col];
    #pragma unroll
    for (int j = 0; j < 4; ++j){ xp0[j] += bx0 + bh0; xp1[j] += bx1 + bh1; }
  }
  __syncthreads();

  // ---- phase 2: pack Wh -> LDS (stays for all 128 steps)
  pack_w(lds, bn, tid, p.Whi, p.Whf, p.Who, p.Whc);
  __syncthreads();

  // ---- recurrent steps
  f32x4 cc = {0.f,0.f,0.f,0.f};
  for (int t = 0; t < T; ++t){
    f32x4 ac0 = {0.f,0.f,0.f,0.f}, ac1 = {0.f,0.f,0.f,0.f};
    if (t > 0){
      const char* aB = p.hb + (((t + 1) & 1) << 20)
                     + (size_t)(rowbase + l15) * 4096 + lhi * 32;
      #pragma unroll 4
      for (int k0 = 0; k0 < 1024; k0 += 32){
        short8 A1 = *(const short8*)(aB + k0 * 4);
        short8 A2 = *(const short8*)(aB + k0 * 4 + 16);
        int s0 = (lin0 + k0 * 2) ^ m;
        int s1 = (lin1 + k0 * 2) ^ m;
        short8 b10 = *(const short8*)(lds + s0);
        short8 b20 = *(const short8*)(lds + 65536 + s0);
        short8 b11 = *(const short8*)(lds + s1);
        short8 b21 = *(const short8*)(lds + 65536 + s1);
        ac0 = __builtin_amdgcn_mfma_f32_16x16x32_bf16(A1, b10, ac0, 0,0,0);
        ac0 = __builtin_amdgcn_mfma_f32_16x16x32_bf16(A2, b10, ac0, 0,0,0);
        ac0 = __builtin_amdgcn_mfma_f32_16x16x32_bf16(A1, b20, ac0, 0,0,0);
        ac1 = __builtin_amdgcn_mfma_f32_16x16x32_bf16(A1, b11, ac1, 0,0,0);
        ac1 = __builtin_amdgcn_mfma_f32_16x16x32_bf16(A2, b11, ac1, 0,0,0);
        ac1 = __builtin_amdgcn_mfma_f32_16x16x32_bf16(A1, b21, ac1, 0,0,0);
      }
    }
    // elementwise update; tile0 lane pair holds (i,f), tile1 (o,c~)
    char* hout = p.hb + ((t & 1) << 20);
    #pragma unroll
    for (int j = 0; j < 4; ++j){
      float p0 = ac0[j] + xp0[j];
      float p1 = ac1[j] + xp1[j];
      float q0 = __shfl_xor(p0, 1);
      float q1 = __shfl_xor(p1, 1);
      float iv = odd ? q0 : p0, fv = odd ? p0 : q0;
      float ov = odd ? q1 : p1, gv = odd ? p1 : q1;
      float cn = sigf(fv) * cc[j] + sigf(iv) * tanh_(gv);
      cc[j] = cn;
      float h = sigf(ov) * tanh_(cn);
      int row = rowbase + lhi * 4 + j;
      if (!odd){
        p.out[((size_t)row * T + t) * H + col] = h;
      } else {
        u16 h1 = f2bf(h);
        u16 h2 = f2bf(h - bf2f(h1));
        char* d = hout + (size_t)row * 4096 + ((col >> 3) << 5) + ((col & 7) << 1);
        *(u16*)d        = h1;
        *(u16*)(d + 16) = h2;
      }
    }
    // grid barrier (skip after last step)
    if (t != T - 1){
      __threadfence();            // drain own stores + L2 writeback (release)
      __syncthreads();
      if (tid == 0){
        __hip_atomic_fetch_add(p.bar, 1u, __ATOMIC_ACQ_REL, __HIP_MEMORY_SCOPE_AGENT);
        u32 tgt = 256u * (u32)(t + 1);
        while (__hip_atomic_load(p.bar, __ATOMIC_ACQUIRE, __HIP_MEMORY_SCOPE_AGENT) < tgt)
          __builtin_amdgcn_s_sleep(4);
      }
      __syncthreads();
      __threadfence();            // acquire: invalidate stale L2 lines
    }
  }
}

extern "C" void kernel_launch(void* const* d_in, const int* in_sizes, int n_in,
                              void* d_out, int out_size, void* d_ws, size_t ws_size,
                              hipStream_t stream){
  (void)in_sizes; (void)n_in; (void)out_size; (void)ws_size;
  P prm;
  prm.x   = (const float*)d_in[0];
  prm.Wxi = (const float*)d_in[1];  prm.bxi = (const float*)d_in[2];
  prm.Whi = (const float*)d_in[3];  prm.bhi = (const float*)d_in[4];
  prm.Wxf = (const float*)d_in[5];  prm.bxf = (const float*)d_in[6];
  prm.Whf = (const float*)d_in[7];  prm.bhf = (const float*)d_in[8];
  prm.Wxo = (const float*)d_in[9];  prm.bxo = (const float*)d_in[10];
  prm.Who = (const float*)d_in[11]; prm.bho = (const float*)d_in[12];
  prm.Wxc = (const float*)d_in[13]; prm.bxc = (const float*)d_in[14];
  prm.Whc = (const float*)d_in[15]; prm.bhc = (const float*)d_in[16];
  prm.out = (float*)d_out;
  prm.hb  = (char*)d_ws;
  prm.bar = (u32*)((char*)d_ws + (2u << 20));

  hipMemsetAsync(prm.bar, 0, 128, stream);
  lstm_kernel<<<256, 512, 0, stream>>>(prm);
}

// Round 3
// 3084.065 us; speedup vs baseline: 4.7833x; 4.7833x over previous
//
#include <hip/hip_runtime.h>
#include <cstdint>
#include <cstddef>

// LSTM decoder B=256,H=1024,T=128. Persistent kernel: 256 blocks x 512 thr
// (1 block/CU). Each block owns 8 cols x 4 gates (packed N=32), weights hi/lo
// bf16 in 128KB LDS (XOR-swizzled), 3-pass bf16 MFMA (h1@W1+h2@W1+h1@W2).
// c/xpre in registers. Cross-step sync: relaxed agent atomics (sc1, no
// per-op cache maintenance) + one acquire fence (buffer_inv) per block/step.
// h is written via relaxed agent-scope stores (write-through to IF).

#define DI __device__ __forceinline__

typedef __attribute__((ext_vector_type(8))) short short8;
typedef __attribute__((ext_vector_type(4))) float f32x4;
typedef unsigned short u16;
typedef unsigned int   u32;

static constexpr int H = 1024;
static constexpr int B = 256;
static constexpr int T = 128;

DI u16 f2bf(float f){
  union { float f; u32 u; } v; v.f = f;
  u32 r = v.u + 0x7fffu + ((v.u >> 16) & 1u);
  return (u16)(r >> 16);
}
DI float bf2f(u16 h){
  union { u32 u; float f; } v; v.u = ((u32)h) << 16; return v.f;
}
DI float sigf(float z){ return 1.0f / (1.0f + __expf(-z)); }
DI float tanh_(float z){
  float e = __expf(-2.0f * fabsf(z));
  float t = (1.0f - e) / (1.0f + e);
  return z < 0.0f ? -t : t;
}

struct P {
  const float *x;
  const float *Wxi,*Wxf,*Wxo,*Wxc;
  const float *Whi,*Whf,*Who,*Whc;
  const float *bxi,*bxf,*bxo,*bxc;
  const float *bhi,*bhf,*bho,*bhc;
  float* out;
  char*  hb;    // 2 x 1MB parity buffers: [row][kb][plane][8] bf16
  u32*   bar;   // grid barrier counter (memset 0 before launch)
};

// Pack the block's 32 packed-N weight rows x K=1024 into LDS (hi plane at 0,
// lo plane at 64KB), XOR-swizzled. Packed row q: tile t=q>>4, qq=q&15,
// gate = t*2 + (qq&1) [t0:(i,f) t1:(o,c)], col = bn*8 + (qq>>1).
DI void pack_w(char* lds, int bn, int tid,
               const float* Wi, const float* Wf, const float* Wo, const float* Wc){
  #pragma unroll
  for (int i = 0; i < 8; ++i){
    int j0 = tid + i * 512;            // 4096 jobs: (q, 16B k-chunk)
    int q  = j0 >> 7;
    int kc = j0 & 127;
    int qq = q & 15;
    const float* Wg = (q & 16) ? ((qq & 1) ? Wc : Wo) : ((qq & 1) ? Wf : Wi);
    const float* src = Wg + (size_t)(bn * 8 + (qq >> 1)) * 1024 + kc * 8;
    f32x4 v0 = *(const f32x4*)(src);
    f32x4 v1 = *(const f32x4*)(src + 4);
    short8 hi, lo;
    #pragma unroll
    for (int e = 0; e < 4; ++e){
      u16 h0 = f2bf(v0[e]); hi[e]     = (short)h0; lo[e]     = (short)f2bf(v0[e] - bf2f(h0));
      u16 h1 = f2bf(v1[e]); hi[4 + e] = (short)h1; lo[4 + e] = (short)f2bf(v1[e] - bf2f(h1));
    }
    int addr = (q * 2048 + kc * 16) ^ ((q & 7) << 4);
    *(short8*)(lds + addr)         = hi;
    *(short8*)(lds + 65536 + addr) = lo;
  }
}

__global__ __launch_bounds__(512, 2) void lstm_kernel(P p){
  __shared__ char lds[131072];
  const int tid  = threadIdx.x;
  const int lane = tid & 63;
  const int w    = tid >> 6;              // wave 0..7 -> M-tile
  const int l15  = lane & 15;
  const int lhi  = lane >> 4;
  const int l7   = lane & 7;
  const int blk  = blockIdx.x;
  const int bn   = blk >> 1;              // col-group 0..127
  const int rg   = blk & 1;               // row-group
  const int rowbase = rg * 128 + w * 16;
  const int col  = bn * 8 + (l15 >> 1);
  const bool odd = (l15 & 1);

  // swizzled-LDS lane constants (B-fragment addressing)
  const int lin0 = l15 * 2048 + lhi * 16;
  const int lin1 = (16 + l15) * 2048 + lhi * 16;
  const int m    = l7 << 4;

  // ---- phase 1: pack Wx -> LDS, compute xpre (this block's 128 rows) in regs
  pack_w(lds, bn, tid, p.Wxi, p.Wxf, p.Wxo, p.Wxc);
  __syncthreads();

  f32x4 xp0 = {0.f,0.f,0.f,0.f}, xp1 = {0.f,0.f,0.f,0.f};
  {
    const float* xr = p.x + (size_t)(rowbase + l15) * 1024 + lhi * 8;
    for (int k0 = 0; k0 < 1024; k0 += 32){
      f32x4 v0 = *(const f32x4*)(xr + k0);
      f32x4 v1 = *(const f32x4*)(xr + k0 + 4);
      short8 a1, a2;
      #pragma unroll
      for (int e = 0; e < 4; ++e){
        u16 h0 = f2bf(v0[e]); a1[e]     = (short)h0; a2[e]     = (short)f2bf(v0[e] - bf2f(h0));
        u16 h1 = f2bf(v1[e]); a1[4 + e] = (short)h1; a2[4 + e] = (short)f2bf(v1[e] - bf2f(h1));
      }
      int s0 = (lin0 + k0 * 2) ^ m;
      int s1 = (lin1 + k0 * 2) ^ m;
      short8 b10 = *(const short8*)(lds + s0);
      short8 b20 = *(const short8*)(lds + 65536 + s0);
      short8 b11 = *(const short8*)(lds + s1);
      short8 b21 = *(const short8*)(lds + 65536 + s1);
      xp0 = __builtin_amdgcn_mfma_f32_16x16x32_bf16(a1, b10, xp0, 0,0,0);
      xp0 = __builtin_amdgcn_mfma_f32_16x16x32_bf16(a2, b10, xp0, 0,0,0);
      xp0 = __builtin_amdgcn_mfma_f32_16x16x32_bf16(a1, b20, xp0, 0,0,0);
      xp1 = __builtin_amdgcn_mfma_f32_16x16x32_bf16(a1, b11, xp1, 0,0,0);
      xp1 = __builtin_amdgcn_mfma_f32_16x16x32_bf16(a2, b11, xp1, 0,0,0);
      xp1 = __builtin_amdgcn_mfma_f32_16x16x32_bf16(a1, b21, xp1, 0,0,0);
    }
    float bx0 = odd ? p.bxf[col] : p.bxi[col];
    float bh0 = odd ? p.bhf[col] : p.bhi[col];
    float bx1 = odd ? p.bxc[col] : p.bxo[col];
    float bh1 = odd ? p.bhc[col] : p.bho[col];
    #pragma unroll
    for (int j = 0; j < 4; ++j){ xp0[j] += bx0 + bh0; xp1[j] += bx1 + bh1; }
  }
  __syncthreads();

  // ---- phase 2: pack Wh -> LDS (stays for all 128 steps)
  pack_w(lds, bn, tid, p.Whi, p.Whf, p.Who, p.Whc);
  __syncthreads();

  // ---- recurrent steps
  f32x4 cc = {0.f,0.f,0.f,0.f};
  for (int t = 0; t < T; ++t){
    f32x4 ac0 = {0.f,0.f,0.f,0.f}, ac1 = {0.f,0.f,0.f,0.f};
    if (t > 0){
      const char* aB = p.hb + (((t + 1) & 1) << 20)
                     + (size_t)(rowbase + l15) * 4096 + lhi * 32;
      #pragma unroll 4
      for (int k0 = 0; k0 < 1024; k0 += 32){
        short8 A1 = *(const short8*)(aB + k0 * 4);
        short8 A2 = *(const short8*)(aB + k0 * 4 + 16);
        int s0 = (lin0 + k0 * 2) ^ m;
        int s1 = (lin1 + k0 * 2) ^ m;
        short8 b10 = *(const short8*)(lds + s0);
        short8 b20 = *(const short8*)(lds + 65536 + s0);
        short8 b11 = *(const short8*)(lds + s1);
        short8 b21 = *(const short8*)(lds + 65536 + s1);
        ac0 = __builtin_amdgcn_mfma_f32_16x16x32_bf16(A1, b10, ac0, 0,0,0);
        ac0 = __builtin_amdgcn_mfma_f32_16x16x32_bf16(A2, b10, ac0, 0,0,0);
        ac0 = __builtin_amdgcn_mfma_f32_16x16x32_bf16(A1, b20, ac0, 0,0,0);
        ac1 = __builtin_amdgcn_mfma_f32_16x16x32_bf16(A1, b11, ac1, 0,0,0);
        ac1 = __builtin_amdgcn_mfma_f32_16x16x32_bf16(A2, b11, ac1, 0,0,0);
        ac1 = __builtin_amdgcn_mfma_f32_16x16x32_bf16(A1, b21, ac1, 0,0,0);
      }
    }
    // elementwise update; tile0 lane pair holds (i,f), tile1 (o,c~)
    char* hout = p.hb + ((t & 1) << 20);
    #pragma unroll
    for (int j = 0; j < 4; ++j){
      float p0 = ac0[j] + xp0[j];
      float p1 = ac1[j] + xp1[j];
      float q0 = __shfl_xor(p0, 1);
      float q1 = __shfl_xor(p1, 1);
      float iv = odd ? q0 : p0, fv = odd ? p0 : q0;
      float ov = odd ? q1 : p1, gv = odd ? p1 : q1;
      float cn = sigf(fv) * cc[j] + sigf(iv) * tanh_(gv);
      cc[j] = cn;
      float h = sigf(ov) * tanh_(cn);
      int row = rowbase + lhi * 4 + j;
      if (!odd){
        p.out[((size_t)row * T + t) * H + col] = h;
      } else {
        u16 h1 = f2bf(h);
        u16 h2 = f2bf(h - bf2f(h1));
        char* d = hout + (size_t)row * 4096 + ((col >> 3) << 5) + ((col & 7) << 1);
        // relaxed agent-scope stores: write-through (sc1) to the IF coherence
        // point -- makes h visible cross-XCD without any L2 writeback fence.
        __hip_atomic_store((u16*)d,        h1, __ATOMIC_RELAXED, __HIP_MEMORY_SCOPE_AGENT);
        __hip_atomic_store((u16*)(d + 16), h2, __ATOMIC_RELAXED, __HIP_MEMORY_SCOPE_AGENT);
      }
    }
    // grid barrier (skip after last step). All ops relaxed (no per-op cache
    // maintenance); one acquire fence (buffer_inv, tag-only) per block/step.
    if (t != T - 1){
      __syncthreads();   // drains each wave's vmcnt -> sc1 stores are at IF
      if (tid == 0){
        __hip_atomic_fetch_add(p.bar, 1u, __ATOMIC_RELAXED, __HIP_MEMORY_SCOPE_AGENT);
        u32 tgt = 256u * (u32)(t + 1);
        while (__hip_atomic_load(p.bar, __ATOMIC_RELAXED, __HIP_MEMORY_SCOPE_AGENT) < tgt)
          __builtin_amdgcn_s_sleep(1);
        __builtin_amdgcn_fence(__ATOMIC_ACQUIRE, "agent");  // drop stale L1/L2 h lines
      }
      __syncthreads();
    }
  }
}

extern "C" void kernel_launch(void* const* d_in, const int* in_sizes, int n_in,
                              void* d_out, int out_size, void* d_ws, size_t ws_size,
                              hipStream_t stream){
  (void)in_sizes; (void)n_in; (void)out_size; (void)ws_size;
  P prm;
  prm.x   = (const float*)d_in[0];
  prm.Wxi = (const float*)d_in[1];  prm.bxi = (const float*)d_in[2];
  prm.Whi = (const float*)d_in[3];  prm.bhi = (const float*)d_in[4];
  prm.Wxf = (const float*)d_in[5];  prm.bxf = (const float*)d_in[6];
  prm.Whf = (const float*)d_in[7];  prm.bhf = (const float*)d_in[8];
  prm.Wxo = (const float*)d_in[9];  prm.bxo = (const float*)d_in[10];
  prm.Who = (const float*)d_in[11]; prm.bho = (const float*)d_in[12];
  prm.Wxc = (const float*)d_in[13]; prm.bxc = (const float*)d_in[14];
  prm.Whc = (const float*)d_in[15]; prm.bhc = (const float*)d_in[16];
  prm.out = (float*)d_out;
  prm.hb  = (char*)d_ws;
  prm.bar = (u32*)((char*)d_ws + (2u << 20));

  hipMemsetAsync(prm.bar, 0, 128, stream);
  lstm_kernel<<<256, 512, 0, stream>>>(prm);
}

// Round 4
// 2741.576 us; speedup vs baseline: 5.3808x; 1.1249x over previous
//
#include <hip/hip_runtime.h>
#include <cstdint>
#include <cstddef>

// LSTM decoder B=256,H=1024,T=128. Persistent kernel: 256 blocks x 1024 thr
// (1 block/CU, 16 waves = 4/SIMD). Each block owns 8 cols x 4 gates (packed
// N=32); weights hi/lo bf16 in 128KB LDS (XOR-swizzled). 3-pass bf16 MFMA
// (h1@W1 + h2@W1 + h1@W2 ~ fp32) with 6 independent acc chains. K-split:
// wave w & w+8 take K halves, partials combined via 16KB LDS scratch.
// Cross-step sync: relaxed agent atomics (sc1), two-level (8+1) counter
// barrier, one acquire fence per block/step. h write-through via sc1 stores.

#define DI __device__ __forceinline__

typedef __attribute__((ext_vector_type(8))) short short8;
typedef __attribute__((ext_vector_type(4))) float f32x4;
typedef unsigned short u16;
typedef unsigned int   u32;

static constexpr int H = 1024;
static constexpr int B = 256;
static constexpr int T = 128;

DI u16 f2bf(float f){
  union { float f; u32 u; } v; v.f = f;
  u32 r = v.u + 0x7fffu + ((v.u >> 16) & 1u);
  return (u16)(r >> 16);
}
DI float bf2f(u16 h){
  union { u32 u; float f; } v; v.u = ((u32)h) << 16; return v.f;
}
DI float sigf(float z){ return 1.0f / (1.0f + __expf(-z)); }
DI float tanh_(float z){
  float e = __expf(-2.0f * fabsf(z));
  float t = (1.0f - e) / (1.0f + e);
  return z < 0.0f ? -t : t;
}

struct P {
  const float *x;
  const float *Wxi,*Wxf,*Wxo,*Wxc;
  const float *Whi,*Whf,*Who,*Whc;
  const float *bxi,*bxf,*bxo,*bxc;
  const float *bhi,*bhf,*bho,*bhc;
  float* out;
  char*  hb;    // 2 x 1MB parity buffers: [row][kb][plane][8] bf16
  u32*   bar;   // 8 counters (stride 32 u32) + root epoch at +256
};

// Pack the block's 32 packed-N weight rows x K=1024 into LDS (hi plane at 0,
// lo plane at 64KB), XOR-swizzled. Packed row q: tile t=q>>4, qq=q&15,
// gate = t*2 + (qq&1) [t0:(i,f) t1:(o,c)], col = bn*8 + (qq>>1).
DI void pack_w(char* lds, int bn, int tid,
               const float* Wi, const float* Wf, const float* Wo, const float* Wc){
  #pragma unroll
  for (int i = 0; i < 4; ++i){
    int j0 = tid + i * 1024;           // 4096 jobs: (q, 16B k-chunk)
    int q  = j0 >> 7;
    int kc = j0 & 127;
    int qq = q & 15;
    const float* Wg = (q & 16) ? ((qq & 1) ? Wc : Wo) : ((qq & 1) ? Wf : Wi);
    const float* src = Wg + (size_t)(bn * 8 + (qq >> 1)) * 1024 + kc * 8;
    f32x4 v0 = *(const f32x4*)(src);
    f32x4 v1 = *(const f32x4*)(src + 4);
    short8 hi, lo;
    #pragma unroll
    for (int e = 0; e < 4; ++e){
      u16 h0 = f2bf(v0[e]); hi[e]     = (short)h0; lo[e]     = (short)f2bf(v0[e] - bf2f(h0));
      u16 h1 = f2bf(v1[e]); hi[4 + e] = (short)h1; lo[4 + e] = (short)f2bf(v1[e] - bf2f(h1));
    }
    int addr = (q * 2048 + kc * 16) ^ ((q & 7) << 4);
    *(short8*)(lds + addr)         = hi;
    *(short8*)(lds + 65536 + addr) = lo;
  }
}

__global__ __launch_bounds__(1024, 4) void lstm_kernel(P p){
  __shared__ char lds[147456];            // 128K weights + 16K combine scratch
  char* scratch = lds + 131072;
  const int tid  = threadIdx.x;
  const int lane = tid & 63;
  const int wv   = tid >> 6;              // 0..15
  const int w8   = wv & 7;                // M-tile
  const int kh   = wv >> 3;               // K-half
  const int l15  = lane & 15;
  const int lhi  = lane >> 4;
  const int l7   = lane & 7;
  const int blk  = blockIdx.x;
  const int bn   = blk >> 1;              // col-group 0..127
  const int rg   = blk & 1;               // row-group
  const int rowbase = rg * 128 + w8 * 16;
  const int col  = bn * 8 + (l15 >> 1);
  const bool odd = (l15 & 1);
  const int kbase = kh * 512;

  // swizzled-LDS lane constants (B-fragment addressing)
  const int lin0 = l15 * 2048 + lhi * 16 + kbase * 2;
  const int lin1 = (16 + l15) * 2048 + lhi * 16 + kbase * 2;
  const int m    = l7 << 4;

  // ---- phase 1: pack Wx -> LDS, compute xpre (this block's 128 rows)
  pack_w(lds, bn, tid, p.Wxi, p.Wxf, p.Wxo, p.Wxc);
  __syncthreads();

  f32x4 xp0 = {0.f,0.f,0.f,0.f}, xp1 = {0.f,0.f,0.f,0.f};
  {
    f32x4 t0a={0,0,0,0},t0b={0,0,0,0},t0c={0,0,0,0};
    f32x4 t1a={0,0,0,0},t1b={0,0,0,0},t1c={0,0,0,0};
    const float* xr = p.x + (size_t)(rowbase + l15) * 1024 + kbase + lhi * 8;
    #pragma unroll 4
    for (int k0 = 0; k0 < 512; k0 += 32){
      f32x4 v0 = *(const f32x4*)(xr + k0);
      f32x4 v1 = *(const f32x4*)(xr + k0 + 4);
      short8 a1, a2;
      #pragma unroll
      for (int e = 0; e < 4; ++e){
        u16 h0 = f2bf(v0[e]); a1[e]     = (short)h0; a2[e]     = (short)f2bf(v0[e] - bf2f(h0));
        u16 h1 = f2bf(v1[e]); a1[4 + e] = (short)h1; a2[4 + e] = (short)f2bf(v1[e] - bf2f(h1));
      }
      int s0 = (lin0 + k0 * 2) ^ m;
      int s1 = (lin1 + k0 * 2) ^ m;
      short8 b10 = *(const short8*)(lds + s0);
      short8 b20 = *(const short8*)(lds + 65536 + s0);
      short8 b11 = *(const short8*)(lds + s1);
      short8 b21 = *(const short8*)(lds + 65536 + s1);
      t0a = __builtin_amdgcn_mfma_f32_16x16x32_bf16(a1, b10, t0a, 0,0,0);
      t1a = __builtin_amdgcn_mfma_f32_16x16x32_bf16(a1, b11, t1a, 0,0,0);
      t0b = __builtin_amdgcn_mfma_f32_16x16x32_bf16(a2, b10, t0b, 0,0,0);
      t1b = __builtin_amdgcn_mfma_f32_16x16x32_bf16(a2, b11, t1b, 0,0,0);
      t0c = __builtin_amdgcn_mfma_f32_16x16x32_bf16(a1, b20, t0c, 0,0,0);
      t1c = __builtin_amdgcn_mfma_f32_16x16x32_bf16(a1, b21, t1c, 0,0,0);
    }
    xp0 = t0a + t0b + t0c;
    xp1 = t1a + t1b + t1c;
  }
  // combine K-halves through LDS scratch
  if (wv >= 8){
    char* d = scratch + (((wv - 8) * 64 + lane) << 5);
    *(f32x4*)d        = xp0;
    *(f32x4*)(d + 16) = xp1;
  }
  __syncthreads();
  if (wv < 8){
    const char* s = scratch + ((wv * 64 + lane) << 5);
    xp0 += *(const f32x4*)s;
    xp1 += *(const f32x4*)(s + 16);
    float bx0 = odd ? p.bxf[col] : p.bxi[col];
    float bh0 = odd ? p.bhf[col] : p.bhi[col];
    float bx1 = odd ? p.bxc[col] : p.bxo[col];
    float bh1 = odd ? p.bhc[col] : p.bho[col];
    #pragma unroll
    for (int j = 0; j < 4; ++j){ xp0[j] += bx0 + bh0; xp1[j] += bx1 + bh1; }
  }
  __syncthreads();

  // ---- phase 2: pack Wh -> LDS (stays for all 128 steps)
  pack_w(lds, bn, tid, p.Whi, p.Whf, p.Who, p.Whc);
  __syncthreads();

  // ---- recurrent steps
  f32x4 cc = {0.f,0.f,0.f,0.f};
  for (int t = 0; t < T; ++t){
    f32x4 r0 = {0.f,0.f,0.f,0.f}, r1 = {0.f,0.f,0.f,0.f};
    if (t > 0){
      f32x4 t0a={0,0,0,0},t0b={0,0,0,0},t0c={0,0,0,0};
      f32x4 t1a={0,0,0,0},t1b={0,0,0,0},t1c={0,0,0,0};
      const char* aB = p.hb + (((t + 1) & 1) << 20)
                     + (size_t)(rowbase + l15) * 4096 + kbase * 4 + lhi * 32;
      short8 A1 = *(const short8*)(aB);
      short8 A2 = *(const short8*)(aB + 16);
      #pragma unroll
      for (int ki = 0; ki < 16; ++ki){
        short8 nA1, nA2;
        if (ki < 15){
          nA1 = *(const short8*)(aB + (ki + 1) * 128);
          nA2 = *(const short8*)(aB + (ki + 1) * 128 + 16);
        }
        int s0 = (lin0 + ki * 64) ^ m;
        int s1 = (lin1 + ki * 64) ^ m;
        short8 b10 = *(const short8*)(lds + s0);
        short8 b20 = *(const short8*)(lds + 65536 + s0);
        short8 b11 = *(const short8*)(lds + s1);
        short8 b21 = *(const short8*)(lds + 65536 + s1);
        t0a = __builtin_amdgcn_mfma_f32_16x16x32_bf16(A1, b10, t0a, 0,0,0);
        t1a = __builtin_amdgcn_mfma_f32_16x16x32_bf16(A1, b11, t1a, 0,0,0);
        t0b = __builtin_amdgcn_mfma_f32_16x16x32_bf16(A2, b10, t0b, 0,0,0);
        t1b = __builtin_amdgcn_mfma_f32_16x16x32_bf16(A2, b11, t1b, 0,0,0);
        t0c = __builtin_amdgcn_mfma_f32_16x16x32_bf16(A1, b20, t0c, 0,0,0);
        t1c = __builtin_amdgcn_mfma_f32_16x16x32_bf16(A1, b21, t1c, 0,0,0);
        A1 = nA1; A2 = nA2;
      }
      r0 = t0a + t0b + t0c;
      r1 = t1a + t1b + t1c;
    }
    // combine K-halves
    if (wv >= 8){
      char* d = scratch + (((wv - 8) * 64 + lane) << 5);
      *(f32x4*)d        = r0;
      *(f32x4*)(d + 16) = r1;
    }
    __syncthreads();
    if (wv < 8){
      const char* s = scratch + ((wv * 64 + lane) << 5);
      r0 += *(const f32x4*)s;
      r1 += *(const f32x4*)(s + 16);
      // elementwise update; tile0 lane pair holds (i,f), tile1 (o,c~)
      char* hout = p.hb + ((t & 1) << 20);
      #pragma unroll
      for (int j = 0; j < 4; ++j){
        float p0 = r0[j] + xp0[j];
        float p1 = r1[j] + xp1[j];
        float q0 = __shfl_xor(p0, 1);
        float q1 = __shfl_xor(p1, 1);
        float iv = odd ? q0 : p0, fv = odd ? p0 : q0;
        float ov = odd ? q1 : p1, gv = odd ? p1 : q1;
        float cn = sigf(fv) * cc[j] + sigf(iv) * tanh_(gv);
        cc[j] = cn;
        float h = sigf(ov) * tanh_(cn);
        int row = rowbase + lhi * 4 + j;
        if (!odd){
          p.out[((size_t)row * T + t) * H + col] = h;
        } else {
          u16 h1 = f2bf(h);
          u16 h2 = f2bf(h - bf2f(h1));
          char* d = hout + (size_t)row * 4096 + ((col >> 3) << 5) + ((col & 7) << 1);
          // relaxed agent-scope write-through: visible cross-XCD w/o wb fence
          __hip_atomic_store((u16*)d,        h1, __ATOMIC_RELAXED, __HIP_MEMORY_SCOPE_AGENT);
          __hip_atomic_store((u16*)(d + 16), h2, __ATOMIC_RELAXED, __HIP_MEMORY_SCOPE_AGENT);
        }
      }
    }
    // two-level grid barrier (skip after last step)
    if (t != T - 1){
      __syncthreads();   // drains vmcnt: all h stores at coherence point
      if (tid == 0){
        int g = blk & 7;
        __hip_atomic_fetch_add(p.bar + g * 32, 1u, __ATOMIC_RELAXED, __HIP_MEMORY_SCOPE_AGENT);
        if (blk < 8){
          u32 tgt = 32u * (u32)(t + 1);
          while (__hip_atomic_load(p.bar + blk * 32, __ATOMIC_RELAXED, __HIP_MEMORY_SCOPE_AGENT) < tgt)
            __builtin_amdgcn_s_sleep(1);
          __hip_atomic_fetch_add(p.bar + 256, 1u, __ATOMIC_RELAXED, __HIP_MEMORY_SCOPE_AGENT);
        }
        u32 rt = 8u * (u32)(t + 1);
        while (__hip_atomic_load(p.bar + 256, __ATOMIC_RELAXED, __HIP_MEMORY_SCOPE_AGENT) < rt)
          __builtin_amdgcn_s_sleep(2);
        __builtin_amdgcn_fence(__ATOMIC_ACQUIRE, "agent");  // drop stale L1/L2 h lines
      }
      __syncthreads();
    }
  }
}

extern "C" void kernel_launch(void* const* d_in, const int* in_sizes, int n_in,
                              void* d_out, int out_size, void* d_ws, size_t ws_size,
                              hipStream_t stream){
  (void)in_sizes; (void)n_in; (void)out_size; (void)ws_size;
  P prm;
  prm.x   = (const float*)d_in[0];
  prm.Wxi = (const float*)d_in[1];  prm.bxi = (const float*)d_in[2];
  prm.Whi = (const float*)d_in[3];  prm.bhi = (const float*)d_in[4];
  prm.Wxf = (const float*)d_in[5];  prm.bxf = (const float*)d_in[6];
  prm.Whf = (const float*)d_in[7];  prm.bhf = (const float*)d_in[8];
  prm.Wxo = (const float*)d_in[9];  prm.bxo = (const float*)d_in[10];
  prm.Who = (const float*)d_in[11]; prm.bho = (const float*)d_in[12];
  prm.Wxc = (const float*)d_in[13]; prm.bxc = (const float*)d_in[14];
  prm.Whc = (const float*)d_in[15]; prm.bhc = (const float*)d_in[16];
  prm.out = (float*)d_out;
  prm.hb  = (char*)d_ws;
  prm.bar = (u32*)((char*)d_ws + (2u << 20));

  hipMemsetAsync(prm.bar, 0, 2048, stream);
  lstm_kernel<<<256, 1024, 0, stream>>>(prm);
}